// Round 1
// baseline (79.673 us; speedup 1.0000x reference)
//
#include <hip/hip_runtime.h>

#define KMAX 64
#define BB 4
#define LL 4096
#define DD 64

// Phase 1: one thread per token -> compute packed LSH code for query AND key.
__global__ void codes_kernel(const float* __restrict__ q,
                             const float* __restrict__ k,
                             const float* __restrict__ W,
                             int* __restrict__ qcodes,
                             int* __restrict__ kcodes) {
    __shared__ float sW[DD * 4];
    for (int i = threadIdx.x; i < DD * 4; i += blockDim.x) sW[i] = W[i];
    __syncthreads();
    int t = blockIdx.x * blockDim.x + threadIdx.x;
    const int n = BB * LL;
    if (t >= n) return;

    #pragma unroll
    for (int s = 0; s < 2; ++s) {
        const float* xp = (s == 0 ? q : k) + (size_t)t * DD;
        float p0 = 0.f, p1 = 0.f, p2 = 0.f, p3 = 0.f;
        #pragma unroll
        for (int d = 0; d < DD; ++d) {
            float x = xp[d];
            if (x > 0.f) {   // binary_quantize: (x > 0) -> 1.0
                p0 += sW[d * 4 + 0];
                p1 += sW[d * 4 + 1];
                p2 += sW[d * 4 + 2];
                p3 += sW[d * 4 + 3];
            }
        }
        // E2LSH hash: floor(proj/2) mod 32.  Python-style mod on power-of-2
        // modulus == two's-complement AND with 31.
        int h0 = ((int)floorf(p0 * 0.5f)) & 31;
        int h1 = ((int)floorf(p1 * 0.5f)) & 31;
        int h2 = ((int)floorf(p2 * 0.5f)) & 31;
        int h3 = ((int)floorf(p3 * 0.5f)) & 31;
        int code = h0 | (h1 << 5) | (h2 << 10) | (h3 << 15);
        (s == 0 ? qcodes : kcodes)[t] = code;
    }
}

// Phase 2: one wave (64 lanes) per query token.  Scan the batch's 4096 key
// codes 64 at a time; ballot equality; matching lanes write their index at
// count + popc(lower-lane mask) -> preserves increasing-j order (matches the
// reference's sort-based first-K selection).  Pad remainder with -1.
__global__ void find_kernel(const int* __restrict__ qcodes,
                            const int* __restrict__ kcodes,
                            int* __restrict__ out) {
    int gtid = blockIdx.x * blockDim.x + threadIdx.x;
    int wave = gtid >> 6;
    int lane = gtid & 63;
    if (wave >= BB * LL) return;
    int b = wave >> 12;                 // wave / LL
    int qc = qcodes[wave];
    const int* kc = kcodes + b * LL;
    int* op = out + (size_t)wave * KMAX;

    int count = 0;
    for (int j0 = 0; j0 < LL && count < KMAX; j0 += 64) {
        int j = j0 + lane;
        int kcv = kc[j];
        bool m = (kcv == qc);
        unsigned long long bal = __ballot(m);
        if (m) {
            int pos = count + __popcll(bal & ((1ull << lane) - 1ull));
            if (pos < KMAX) op[pos] = j;
        }
        count += __popcll(bal);
    }
    // tail fill with -1 (each lane writes at most one slot since KMAX == 64)
    int p = count + lane;
    if (p < KMAX) op[p] = -1;
}

extern "C" void kernel_launch(void* const* d_in, const int* in_sizes, int n_in,
                              void* d_out, int out_size, void* d_ws, size_t ws_size,
                              hipStream_t stream) {
    const float* q = (const float*)d_in[0];
    const float* k = (const float*)d_in[1];
    const float* W = (const float*)d_in[2];
    int* out = (int*)d_out;
    int* qcodes = (int*)d_ws;
    int* kcodes = qcodes + BB * LL;

    const int n = BB * LL;                       // 16384 tokens
    codes_kernel<<<(n + 255) / 256, 256, 0, stream>>>(q, k, W, qcodes, kcodes);

    const int total_threads = n * 64;            // one wave per query
    find_kernel<<<(total_threads + 255) / 256, 256, 0, stream>>>(qcodes, kcodes, out);
}

// Round 2
// 27.161 us; speedup vs baseline: 2.9333x; 2.9333x over previous
//
#include <hip/hip_runtime.h>

#define KMAX 64
#define BB 4
#define LL 4096
#define DD 64
#define TOK (BB * LL)   // 16384 tokens per side

// Phase 1: one thread per token-side (q or k). 32768 threads, block=64
// -> 512 blocks -> ~2 blocks/CU (vs 64 blocks total before).
// Accumulation is STRICTLY sequential d=0..63 (bitwise-matches the numpy
// reference: round-1 absmax was exactly 0.0 with this order; do not replace
// with a tree reduction).
__global__ __launch_bounds__(64) void codes_kernel(
        const float* __restrict__ q,
        const float* __restrict__ k,
        const float* __restrict__ W,
        int* __restrict__ codes /* [0,TOK)=qcodes, [TOK,2*TOK)=kcodes */) {
    __shared__ float sW[DD * 4];
    int lane = threadIdx.x;   // block = 64 = one wave
    #pragma unroll
    for (int i = 0; i < 4; ++i) sW[i * 64 + lane] = W[i * 64 + lane];
    __syncthreads();

    int u = blockIdx.x * 64 + lane;          // token-side id, grid covers 2*TOK exactly
    const float* src = (u < TOK) ? q : k;
    int t = u & (TOK - 1);

    // 16 independent float4 loads (token rows are 256B-aligned)
    const float4* xp = (const float4*)(src + (size_t)t * DD);
    float4 x[16];
    #pragma unroll
    for (int i = 0; i < 16; ++i) x[i] = xp[i];

    float p0 = 0.f, p1 = 0.f, p2 = 0.f, p3 = 0.f;
    const float4* wrow = (const float4*)sW;
    #pragma unroll
    for (int d = 0; d < DD; ++d) {
        float xv = ((const float*)x)[d];         // d is compile-time (full unroll)
        float b = (xv > 0.f) ? 1.0f : 0.0f;      // binary_quantize
        float4 w = wrow[d];                      // ds_read_b128, wave-uniform broadcast
        // fmaf(1,w,p) == p+w exactly; fmaf(0,w,p) == p exactly -> identical
        // to the conditional-add order that verified bitwise in round 1.
        p0 = fmaf(b, w.x, p0);
        p1 = fmaf(b, w.y, p1);
        p2 = fmaf(b, w.z, p2);
        p3 = fmaf(b, w.w, p3);
    }
    // E2LSH: floor(p/2) mod 32; Python mod on pow2 == two's-complement AND.
    int h0 = ((int)floorf(p0 * 0.5f)) & 31;
    int h1 = ((int)floorf(p1 * 0.5f)) & 31;
    int h2 = ((int)floorf(p2 * 0.5f)) & 31;
    int h3 = ((int)floorf(p3 * 0.5f)) & 31;
    codes[u] = h0 | (h1 << 5) | (h2 << 10) | (h3 << 15);
}

// Phase 2: one wave per query. Same proven ballot/popc ordering per 64-chunk,
// but 4 chunks (256 j's) per loop iteration: the 4 loads issue back-to-back
// (independent), amortizing load latency and loop overhead 4x. Chunk c covers
// the CONTIGUOUS range [j0+64c, j0+64c+64) so increasing-j order is preserved
// exactly as before.
__global__ void find_kernel(const int* __restrict__ qcodes,
                            const int* __restrict__ kcodes,
                            int* __restrict__ out) {
    int gtid = blockIdx.x * blockDim.x + threadIdx.x;
    int wave = gtid >> 6;
    int lane = gtid & 63;
    if (wave >= BB * LL) return;
    int b = wave >> 12;
    int qc = qcodes[wave];
    const int* kc = kcodes + b * LL;
    int* op = out + (size_t)wave * KMAX;
    unsigned long long lowmask = (1ull << lane) - 1ull;

    int count = 0;
    for (int j0 = 0; j0 < LL && count < KMAX; j0 += 256) {
        int k0 = kc[j0 + lane];
        int k1 = kc[j0 + 64 + lane];
        int k2 = kc[j0 + 128 + lane];
        int k3 = kc[j0 + 192 + lane];
        int kv[4] = {k0, k1, k2, k3};
        #pragma unroll
        for (int c = 0; c < 4; ++c) {
            bool m = (kv[c] == qc);
            unsigned long long bal = __ballot(m);
            if (m) {
                int pos = count + __popcll(bal & lowmask);
                if (pos < KMAX) op[pos] = j0 + c * 64 + lane;
            }
            count += __popcll(bal);
        }
    }
    // tail fill with -1; if count >= KMAX nothing to fill (guard covers it)
    int p = count + lane;
    if (p < KMAX) op[p] = -1;
}

extern "C" void kernel_launch(void* const* d_in, const int* in_sizes, int n_in,
                              void* d_out, int out_size, void* d_ws, size_t ws_size,
                              hipStream_t stream) {
    const float* q = (const float*)d_in[0];
    const float* k = (const float*)d_in[1];
    const float* W = (const float*)d_in[2];
    int* out = (int*)d_out;
    int* codes = (int*)d_ws;                 // [2*TOK] ints
    int* qcodes = codes;
    int* kcodes = codes + TOK;

    codes_kernel<<<(2 * TOK) / 64, 64, 0, stream>>>(q, k, W, codes);

    const int total_threads = TOK * 64;      // one wave per query
    find_kernel<<<(total_threads + 255) / 256, 256, 0, stream>>>(qcodes, kcodes, out);
}